// Round 2
// baseline (9235.118 us; speedup 1.0000x reference)
//
#include <hip/hip_runtime.h>
#include <cstdint>
#include <cstddef>

#define EMB    512
#define HID    512
#define NCLASS 50257
#define BATCH  64
#define STEPS  256
#define FOURH  2048
#define HPAD   520   // padded fp16 row stride for LDS h/Wh tiles (1040 B: 16B-aligned, distinct bank groups)

typedef __attribute__((ext_vector_type(8))) short    bf16x8;
typedef __attribute__((ext_vector_type(4))) float    f32x4;
typedef __attribute__((ext_vector_type(2))) _Float16 h2v;
typedef __attribute__((ext_vector_type(8))) _Float16 h8v;

union H8 { h8v v; h2v p[4]; uint4 u; };

__device__ __forceinline__ unsigned short f2bf(float f) {
    union { float f; unsigned int u; } v; v.f = f;
    unsigned int u = v.u;
    return (unsigned short)((u + 0x7fffu + ((u >> 16) & 1u)) >> 16);
}

__device__ __forceinline__ float fdot2f(h2v a, h2v b, float c) {
#if __has_builtin(__builtin_amdgcn_fdot2)
    return __builtin_amdgcn_fdot2(a, b, c, false);
#else
    return fmaf((float)a[0], (float)b[0], fmaf((float)a[1], (float)b[1], c));
#endif
}

// ---------------- prep kernels ----------------

__global__ void k_bias(const float* __restrict__ bi, const float* __restrict__ bh,
                       float* __restrict__ bias) {
    int i = blockIdx.x * 256 + threadIdx.x;
    if (i < FOURH) bias[i] = bi[i] + bh[i];
}

// Wi [512][2048] fp32 -> WiT [2048][512] bf16  (B^T layout for MFMA B-frags)
__global__ void k_wit(const float* __restrict__ Wi, unsigned short* __restrict__ WiT) {
    int n = blockIdx.x;        // 0..2047
    int l = threadIdx.x;       // 0..63
    int k0 = l * 8;
    unsigned short t[8];
#pragma unroll
    for (int i = 0; i < 8; i++)
        t[i] = f2bf(Wi[(size_t)(k0 + i) * FOURH + n]);
    uint4 v;
    v.x = (unsigned)t[0] | ((unsigned)t[1] << 16);
    v.y = (unsigned)t[2] | ((unsigned)t[3] << 16);
    v.z = (unsigned)t[4] | ((unsigned)t[5] << 16);
    v.w = (unsigned)t[6] | ((unsigned)t[7] << 16);
    *(uint4*)(WiT + (size_t)n * EMB + k0) = v;
}

// Wh [512][2048] fp32 -> WhT [2048 cols][512 j] fp16 (transposed, per-col contiguous)
__global__ void k_whT(const float* __restrict__ Wh, _Float16* __restrict__ WhT) {
    int n = blockIdx.x;        // col 0..2047
    int l = threadIdx.x;       // 0..63
    int j0 = l * 8;
    h8v r;
#pragma unroll
    for (int i = 0; i < 8; i++)
        r[i] = (_Float16)Wh[(size_t)(j0 + i) * FOURH + n];
    *(h8v*)(WhT + (size_t)n * HID + j0) = r;
}

// XA[m][k] = bf16(emb[X[b][t]][k]),  m = t*64 + b
__global__ void k_gather(const int* __restrict__ X, const float* __restrict__ emb,
                         unsigned short* __restrict__ XA) {
    int chunk = blockIdx.x * 256 + threadIdx.x;  // 0..1048575 (8 elems each)
    int m  = chunk >> 6;
    int c8 = (chunk & 63) * 8;
    int t = m >> 6, b = m & 63;
    int row = X[b * STEPS + t];
    const float4* src = (const float4*)(emb + (size_t)row * EMB + c8);
    float4 f0 = src[0], f1 = src[1];
    uint4 v;
    v.x = (unsigned)f2bf(f0.x) | ((unsigned)f2bf(f0.y) << 16);
    v.y = (unsigned)f2bf(f0.z) | ((unsigned)f2bf(f0.w) << 16);
    v.z = (unsigned)f2bf(f1.x) | ((unsigned)f2bf(f1.y) << 16);
    v.w = (unsigned)f2bf(f1.z) | ((unsigned)f2bf(f1.w) << 16);
    *(uint4*)(XA + (size_t)m * EMB + c8) = v;
}

// zero-init hG buffers + barrier state (ws is poisoned 0xAA before every launch)
__global__ void k_zero(int* __restrict__ p, int n) {
    int i = blockIdx.x * 256 + threadIdx.x;
    if (i < n) p[i] = 0;
}

// ---------------- K1: XW = XA @ Wi + (bi+bh), bf16 MFMA ----------------
__global__ __launch_bounds__(256) void k_gemm1(const unsigned short* __restrict__ XA,
                                               const unsigned short* __restrict__ WiT,
                                               const float* __restrict__ bias,
                                               float* __restrict__ XW) {
    __shared__ unsigned short Al[64 * 48];
    __shared__ unsigned short Bl[64 * 48];
    const int m0 = blockIdx.y * 64;
    const int n0 = blockIdx.x * 64;
    const int tid  = threadIdx.x;
    const int w    = tid >> 6;
    const int lane = tid & 63;
    const int quad = lane >> 4;
    const int l16  = lane & 15;
    const int ar = tid >> 2;
    const int ac = (tid & 3) * 8;

    f32x4 acc[4];
#pragma unroll
    for (int i = 0; i < 4; i++) acc[i] = (f32x4){0.f, 0.f, 0.f, 0.f};

    for (int kk = 0; kk < 16; kk++) {
        const int k0 = kk * 32;
        __syncthreads();
        *(uint4*)(&Al[ar * 48 + ac]) = *(const uint4*)(XA  + (size_t)(m0 + ar) * EMB + k0 + ac);
        *(uint4*)(&Bl[ar * 48 + ac]) = *(const uint4*)(WiT + (size_t)(n0 + ar) * EMB + k0 + ac);
        __syncthreads();
        bf16x8 afrag = *(const bf16x8*)(&Al[(w * 16 + l16) * 48 + quad * 8]);
#pragma unroll
        for (int nt = 0; nt < 4; nt++) {
            bf16x8 bfrag = *(const bf16x8*)(&Bl[(nt * 16 + l16) * 48 + quad * 8]);
            acc[nt] = __builtin_amdgcn_mfma_f32_16x16x32_bf16(afrag, bfrag, acc[nt], 0, 0, 0);
        }
    }
    const int mrow = m0 + w * 16 + quad * 4;
#pragma unroll
    for (int nt = 0; nt < 4; nt++) {
        int n = n0 + nt * 16 + l16;
        float bv = bias[n];
#pragma unroll
        for (int r = 0; r < 4; r++)
            XW[(size_t)(mrow + r) * FOURH + n] = acc[nt][r] + bv;
    }
}

// ---------------- K2: persistent col-partitioned LSTM recurrence ----------------
// 256 blocks x 256 thr. Block k owns units {2k, 2k+1} = 8 gate cols; its Wh slice
// (8x512 fp16) lives in LDS for all 256 steps. Per step: stage h (64KB fp16) from a
// double-buffered global h, dot via v_dot2_f32_f16, fuse gates (c in regs), write
// 1KB h_new, 2-level device-scope atomic grid barrier.
__global__ __launch_bounds__(256) void k_rec2(const float* __restrict__ XW,
                                              const _Float16* __restrict__ WhT,
                                              _Float16* __restrict__ hG,   // 2 x [64][512]
                                              int* __restrict__ bar,
                                              float* __restrict__ hfinal) {
    __shared__ _Float16 WhL[8 * HPAD];     //  8320 B
    __shared__ _Float16 hL[64 * HPAD];     // 66560 B
    __shared__ float    preL[8 * 68];      //  2176 B

    const int tid = threadIdx.x;
    const int blk = blockIdx.x;
    const int u0  = blk * 2;
    const int w = tid >> 6, l = tid & 63;
    const int colL = l >> 3, bsub = l & 7;
    const int b0 = w * 16 + bsub, b1 = b0 + 8;
    const int gcol = (colL >> 1) * 512 + u0 + (colL & 1);   // gate-major global col

    // Wh slice -> LDS (once): 8 rows x 1024 B, 512 x 16B chunks
#pragma unroll
    for (int it = 0; it < 2; it++) {
        int id = it * 256 + tid;
        int r = id >> 6, off = id & 63;
        int gr = (r >> 1) * 512 + u0 + (r & 1);
        *(uint4*)((char*)WhL + r * (HPAD * 2) + off * 16) =
            *(const uint4*)((const char*)WhT + (size_t)gr * (HID * 2) + off * 16);
    }

    float creg = 0.f;                  // threads 0..127 own (unit q=tid&1, batch b=tid>>1)
    const int uq = tid & 1, ub = tid >> 1;

    for (int t = 0; t < STEPS; t++) {
        // stage h[t&1]: 64 rows x 1024 B
        const char* hsrc = (const char*)hG + (size_t)(t & 1) * 65536;
#pragma unroll
        for (int it = 0; it < 16; it++) {
            int id = it * 256 + tid;
            int r = id >> 6, off = id & 63;
            *(uint4*)((char*)hL + r * (HPAD * 2) + off * 16) =
                *(const uint4*)(hsrc + r * 1024 + off * 16);
        }
        float x0 = XW[(size_t)(t * 64 + b0) * FOURH + gcol];
        float x1 = XW[(size_t)(t * 64 + b1) * FOURH + gcol];
        __syncthreads();

        float a0 = 0.f, a1 = 0.f;
        const h8v* wrow = (const h8v*)((const char*)WhL + colL * (HPAD * 2));
        const h8v* h0r  = (const h8v*)((const char*)hL + b0 * (HPAD * 2));
        const h8v* h1r  = (const h8v*)((const char*)hL + b1 * (HPAD * 2));
#pragma unroll 8
        for (int jo = 0; jo < 64; jo++) {
            H8 wv, hv0, hv1;
            wv.v = wrow[jo]; hv0.v = h0r[jo]; hv1.v = h1r[jo];
#pragma unroll
            for (int k = 0; k < 4; k++) {
                a0 = fdot2f(hv0.p[k], wv.p[k], a0);
                a1 = fdot2f(hv1.p[k], wv.p[k], a1);
            }
        }
        a0 += x0; a1 += x1;
        preL[colL * 68 + b0] = a0;
        preL[colL * 68 + b1] = a1;
        __syncthreads();

        if (tid < 128) {
            float iv = preL[(0 + uq) * 68 + ub];
            float fv = preL[(2 + uq) * 68 + ub];
            float gv = preL[(4 + uq) * 68 + ub];
            float ov = preL[(6 + uq) * 68 + ub];
            float is = 1.f / (1.f + __expf(-iv));
            float fs = 1.f / (1.f + __expf(-fv));
            float gt = tanhf(gv);
            float os = 1.f / (1.f + __expf(-ov));
            creg = fs * creg + is * gt;
            float hnew = os * tanhf(creg);
            _Float16* hdst = hG + (size_t)((t + 1) & 1) * 32768;
            hdst[ub * HID + u0 + uq] = (_Float16)hnew;
            if (t == STEPS - 1) hfinal[ub * HID + u0 + uq] = hnew;
        }
        __syncthreads();   // all stores issued+drained (syncthreads waits vmcnt(0))

        // ---- 2-level grid barrier: 8 group counters -> root -> 8 release words ----
        if (tid == 0) {
            __threadfence();
            const int e = t + 1;
            const int g = blk & 7;
            int a = __hip_atomic_fetch_add(&bar[g * 16], 1, __ATOMIC_RELEASE,
                                           __HIP_MEMORY_SCOPE_AGENT);
            if (a == 32 * e - 1) {
                int r = __hip_atomic_fetch_add(&bar[128], 1, __ATOMIC_RELEASE,
                                               __HIP_MEMORY_SCOPE_AGENT);
                if (r == 8 * e - 1) {
#pragma unroll
                    for (int gg = 0; gg < 8; gg++)
                        __hip_atomic_store(&bar[144 + gg * 16], e, __ATOMIC_RELEASE,
                                           __HIP_MEMORY_SCOPE_AGENT);
                }
            }
            while (__hip_atomic_load(&bar[144 + g * 16], __ATOMIC_ACQUIRE,
                                     __HIP_MEMORY_SCOPE_AGENT) < e)
                __builtin_amdgcn_s_sleep(2);
        }
        __syncthreads();
    }
}

// ---------------- K3: out = h @ Wout^T + bout ----------------
__global__ __launch_bounds__(128) void k_out(const float* __restrict__ Wout,
                                             const float* __restrict__ bout,
                                             const float* __restrict__ hfinal,
                                             float* __restrict__ out) {
    __shared__ float hl[BATCH * 128];
    const int tid = threadIdx.x;
    const int n = blockIdx.x * 128 + tid;
    const bool valid = n < NCLASS;
    float acc[BATCH];
#pragma unroll
    for (int b = 0; b < BATCH; b++) acc[b] = 0.f;
    const float4* W4 = (const float4*)Wout;
    const float4* h4 = (const float4*)hfinal;
    float4* hl4 = (float4*)hl;

    for (int kq = 0; kq < 4; kq++) {
        __syncthreads();
#pragma unroll
        for (int i = 0; i < 16; i++) {
            int f = i * 128 + tid;
            int b = f >> 5, kk = f & 31;
            hl4[f] = h4[b * 128 + kq * 32 + kk];
        }
        __syncthreads();
        if (valid) {
            for (int kk = 0; kk < 32; kk++) {
                float4 wv = W4[(size_t)n * 128 + kq * 32 + kk];
#pragma unroll
                for (int b = 0; b < BATCH; b++) {
                    float4 hv = hl4[b * 32 + kk];
                    acc[b] = fmaf(wv.x, hv.x, acc[b]);
                    acc[b] = fmaf(wv.y, hv.y, acc[b]);
                    acc[b] = fmaf(wv.z, hv.z, acc[b]);
                    acc[b] = fmaf(wv.w, hv.w, acc[b]);
                }
            }
        }
    }
    if (valid) {
        float bv = bout[n];
        for (int b = 0; b < BATCH; b++)
            out[(size_t)b * NCLASS + n] = acc[b] + bv;
    }
}

// ---------------- launch ----------------

extern "C" void kernel_launch(void* const* d_in, const int* in_sizes, int n_in,
                              void* d_out, int out_size, void* d_ws, size_t ws_size,
                              hipStream_t stream) {
    const int*   X    = (const int*)  d_in[0];
    const float* emb  = (const float*)d_in[1];
    const float* Wi   = (const float*)d_in[2];
    const float* Wh   = (const float*)d_in[3];
    const float* bi   = (const float*)d_in[4];
    const float* bh   = (const float*)d_in[5];
    const float* Wout = (const float*)d_in[10];
    const float* bout = (const float*)d_in[11];
    float* out = (float*)d_out;

    char* w = (char*)d_ws;
    float*          XW     = (float*)(w);                           // 134217728 B
    unsigned short* XA     = (unsigned short*)(w + 134217728);      //  16777216 B (K1 only)
    // hG/bar aliased into XA tail — used only after k_gemm1 is done with XA:
    _Float16*       hG     = (_Float16*)(w + 150732800);            //    131072 B (2 bufs)
    int*            bar    = (int*)(w + 150863872);                 //      4096 B
    unsigned short* WiT    = (unsigned short*)(w + 150994944);      //   2097152 B
    _Float16*       WhT    = (_Float16*)(w + 153092096);            //   2097152 B
    float*          bias   = (float*)(w + 155189248);               //      8192 B
    float*          hfinal = (float*)(w + 155197440);               //    131072 B
    // total footprint unchanged from round 1: 155328512 B

    k_bias  <<<8,    256, 0, stream>>>(bi, bh, bias);
    k_wit   <<<2048,  64, 0, stream>>>(Wi, WiT);
    k_whT   <<<2048,  64, 0, stream>>>(Wh, WhT);
    k_gather<<<4096, 256, 0, stream>>>(X, emb, XA);
    k_gemm1 <<<dim3(32, 256), 256, 0, stream>>>(XA, WiT, bias, XW);
    k_zero  <<<132,  256, 0, stream>>>((int*)hG, 33792);            // hG[2] + bar
    k_rec2  <<<256,  256, 0, stream>>>(XW, WhT, hG, bar, hfinal);
    k_out   <<<393,  128, 0, stream>>>(Wout, bout, hfinal, out);
}

// Round 3
// 1922.219 us; speedup vs baseline: 4.8044x; 4.8044x over previous
//
#include <hip/hip_runtime.h>
#include <cstdint>
#include <cstddef>

#define EMB    512
#define HID    512
#define NCLASS 50257
#define BATCH  64
#define STEPS  256
#define FOURH  2048
#define HPAD   520   // fp16 row stride: 1040 B = 65 x 16B units (odd -> even 16B-column-group spread)

typedef __attribute__((ext_vector_type(8))) short    bf16x8;
typedef __attribute__((ext_vector_type(4))) float    f32x4;
typedef __attribute__((ext_vector_type(2))) _Float16 h2v;
typedef __attribute__((ext_vector_type(8))) _Float16 h8v;

union H8 { h8v v; h2v p[4]; uint4 u; };

__device__ __forceinline__ unsigned short f2bf(float f) {
    union { float f; unsigned int u; } v; v.f = f;
    unsigned int u = v.u;
    return (unsigned short)((u + 0x7fffu + ((u >> 16) & 1u)) >> 16);
}

__device__ __forceinline__ float fdot2f(h2v a, h2v b, float c) {
#if __has_builtin(__builtin_amdgcn_fdot2)
    return __builtin_amdgcn_fdot2(a, b, c, false);
#else
    return fmaf((float)a[0], (float)b[0], fmaf((float)a[1], (float)b[1], c));
#endif
}

// ---------------- prep kernels ----------------

__global__ void k_bias(const float* __restrict__ bi, const float* __restrict__ bh,
                       float* __restrict__ bias) {
    int i = blockIdx.x * 256 + threadIdx.x;
    if (i < FOURH) bias[i] = bi[i] + bh[i];
}

// Wi [512][2048] fp32 -> WiT [2048][512] bf16
__global__ void k_wit(const float* __restrict__ Wi, unsigned short* __restrict__ WiT) {
    int n = blockIdx.x;
    int l = threadIdx.x;
    int k0 = l * 8;
    unsigned short t[8];
#pragma unroll
    for (int i = 0; i < 8; i++)
        t[i] = f2bf(Wi[(size_t)(k0 + i) * FOURH + n]);
    uint4 v;
    v.x = (unsigned)t[0] | ((unsigned)t[1] << 16);
    v.y = (unsigned)t[2] | ((unsigned)t[3] << 16);
    v.z = (unsigned)t[4] | ((unsigned)t[5] << 16);
    v.w = (unsigned)t[6] | ((unsigned)t[7] << 16);
    *(uint4*)(WiT + (size_t)n * EMB + k0) = v;
}

// Wh [512][2048] fp32 -> WhT [2048 cols][512 j] fp16
__global__ void k_whT(const float* __restrict__ Wh, _Float16* __restrict__ WhT) {
    int n = blockIdx.x;
    int l = threadIdx.x;
    int j0 = l * 8;
    h8v r;
#pragma unroll
    for (int i = 0; i < 8; i++)
        r[i] = (_Float16)Wh[(size_t)(j0 + i) * FOURH + n];
    *(h8v*)(WhT + (size_t)n * HID + j0) = r;
}

// XA[m][k] = bf16(emb[X[b][t]][k]),  m = t*64 + b
__global__ void k_gather(const int* __restrict__ X, const float* __restrict__ emb,
                         unsigned short* __restrict__ XA) {
    int chunk = blockIdx.x * 256 + threadIdx.x;
    int m  = chunk >> 6;
    int c8 = (chunk & 63) * 8;
    int t = m >> 6, b = m & 63;
    int row = X[b * STEPS + t];
    const float4* src = (const float4*)(emb + (size_t)row * EMB + c8);
    float4 f0 = src[0], f1 = src[1];
    uint4 v;
    v.x = (unsigned)f2bf(f0.x) | ((unsigned)f2bf(f0.y) << 16);
    v.y = (unsigned)f2bf(f0.z) | ((unsigned)f2bf(f0.w) << 16);
    v.z = (unsigned)f2bf(f1.x) | ((unsigned)f2bf(f1.y) << 16);
    v.w = (unsigned)f2bf(f1.z) | ((unsigned)f2bf(f1.w) << 16);
    *(uint4*)(XA + (size_t)m * EMB + c8) = v;
}

__global__ void k_zero(int* __restrict__ p, int n) {
    int i = blockIdx.x * 256 + threadIdx.x;
    if (i < n) p[i] = 0;
}

// ---------------- K1: XWT[t][col][b] = (XA @ Wi)^T + (bi+bh) ----------------
// Operand-swapped MFMA: A-side = WiT rows (gate cols), B-side = XA rows (batches)
// -> D rows = gate cols, D cols = batches -> coalesced transposed stores.
__global__ __launch_bounds__(256) void k_gemm1(const unsigned short* __restrict__ XA,
                                               const unsigned short* __restrict__ WiT,
                                               const float* __restrict__ bias,
                                               float* __restrict__ XWT) {
    __shared__ unsigned short Al[64 * 48];
    __shared__ unsigned short Bl[64 * 48];
    const int t  = blockIdx.y;          // m-tile == one timestep (64 batches)
    const int m0 = t * 64;
    const int n0 = blockIdx.x * 64;
    const int tid  = threadIdx.x;
    const int w    = tid >> 6;
    const int lane = tid & 63;
    const int quad = lane >> 4;
    const int l16  = lane & 15;
    const int ar = tid >> 2;
    const int ac = (tid & 3) * 8;

    f32x4 acc[4];
#pragma unroll
    for (int i = 0; i < 4; i++) acc[i] = (f32x4){0.f, 0.f, 0.f, 0.f};

    for (int kk = 0; kk < 16; kk++) {
        const int k0 = kk * 32;
        __syncthreads();
        *(uint4*)(&Al[ar * 48 + ac]) = *(const uint4*)(XA  + (size_t)(m0 + ar) * EMB + k0 + ac);
        *(uint4*)(&Bl[ar * 48 + ac]) = *(const uint4*)(WiT + (size_t)(n0 + ar) * EMB + k0 + ac);
        __syncthreads();
        bf16x8 afrag = *(const bf16x8*)(&Bl[(w * 16 + l16) * 48 + quad * 8]);  // gate cols
#pragma unroll
        for (int mt = 0; mt < 4; mt++) {
            bf16x8 bfrag = *(const bf16x8*)(&Al[(mt * 16 + l16) * 48 + quad * 8]);  // batches
            acc[mt] = __builtin_amdgcn_mfma_f32_16x16x32_bf16(afrag, bfrag, acc[mt], 0, 0, 0);
        }
    }
    // D: row(quad*4+r) = gate col n_local (within w*16 subtile), col(l16) = batch
    float bv[4];
#pragma unroll
    for (int r = 0; r < 4; r++) bv[r] = bias[n0 + w * 16 + quad * 4 + r];
#pragma unroll
    for (int mt = 0; mt < 4; mt++)
#pragma unroll
        for (int r = 0; r < 4; r++)
            XWT[((size_t)t * FOURH + n0 + w * 16 + quad * 4 + r) * 64 + mt * 16 + l16]
                = acc[mt][r] + bv[r];
}

// ---------------- K2: one kernel per LSTM step ----------------
// 256 blocks x 256 thr; block k owns units {2k,2k+1} (8 gate cols).
// Kernel boundary = grid barrier + coherence. No atomics, no fences.
__global__ __launch_bounds__(256) void k_step(const float* __restrict__ XWT,
                                              const _Float16* __restrict__ WhT,
                                              _Float16* __restrict__ hG,   // 2 x [64][512]
                                              float* __restrict__ cG,     // [64][512]
                                              float* __restrict__ hfinal,
                                              int t) {
    __shared__ _Float16 WhL[8 * HPAD];      //  8320 B
    __shared__ _Float16 hL[76 * HPAD];      // 79040 B (padded >80KB total -> 1 block/CU)
    __shared__ float    redL[2 * 8 * 64];   //  4096 B  [jh][colL][b]

    const int tid = threadIdx.x;
    const int u0  = blockIdx.x * 2;

    // early-issue gate-thread inputs (coalesced XWT reads; c state)
    const int uq = tid & 1, ub = tid >> 1;
    float xw[4], cold = 0.f;
    if (tid < 128) {
        cold = cG[ub * HID + u0 + uq];
#pragma unroll
        for (int g = 0; g < 4; g++)
            xw[g] = XWT[((size_t)t * FOURH + g * 512 + u0 + uq) * 64 + ub];
    }

    // stage Wh slice (8 rows x 1KB) + h[t&1] (64 rows x 1KB)
#pragma unroll
    for (int it = 0; it < 2; it++) {
        int id = it * 256 + tid;
        int r = id >> 6, off = id & 63;
        int gr = (r >> 1) * 512 + u0 + (r & 1);
        *(uint4*)((char*)WhL + r * (HPAD * 2) + off * 16) =
            *(const uint4*)((const char*)WhT + (size_t)gr * (HID * 2) + off * 16);
    }
    const char* hsrc = (const char*)hG + (size_t)(t & 1) * 65536;
#pragma unroll
    for (int it = 0; it < 16; it++) {
        int id = it * 256 + tid;
        int r = id >> 6, off = id & 63;
        *(uint4*)((char*)hL + r * (HPAD * 2) + off * 16) =
            *(const uint4*)(hsrc + r * 1024 + off * 16);
    }
    __syncthreads();

    // dot: thread = (g2: col pair, bp: batch pair, jh: j half); 4 accumulators
    const int id7 = tid & 127;
    const int jh  = tid >> 7;            // 0/1 -> j offset jh*256
    const int bp  = id7 & 31;            // batches bp, bp+32
    const int g2  = id7 >> 5;            // 0..3 -> LDS Wh rows 2g2, 2g2+1
    const h8v* w0r = (const h8v*)((const char*)WhL + (2 * g2)     * (HPAD * 2)) + jh * 32;
    const h8v* w1r = (const h8v*)((const char*)WhL + (2 * g2 + 1) * (HPAD * 2)) + jh * 32;
    const h8v* h0r = (const h8v*)((const char*)hL  + bp           * (HPAD * 2)) + jh * 32;
    const h8v* h1r = (const h8v*)((const char*)hL  + (bp + 32)    * (HPAD * 2)) + jh * 32;
    float a00 = 0.f, a01 = 0.f, a10 = 0.f, a11 = 0.f;
#pragma unroll 4
    for (int jo = 0; jo < 32; jo++) {
        H8 wv0, wv1, hv0, hv1;
        wv0.v = w0r[jo]; wv1.v = w1r[jo]; hv0.v = h0r[jo]; hv1.v = h1r[jo];
#pragma unroll
        for (int k = 0; k < 4; k++) {
            a00 = fdot2f(hv0.p[k], wv0.p[k], a00);
            a01 = fdot2f(hv1.p[k], wv0.p[k], a01);
            a10 = fdot2f(hv0.p[k], wv1.p[k], a10);
            a11 = fdot2f(hv1.p[k], wv1.p[k], a11);
        }
    }
    redL[jh * 512 + (2 * g2)     * 64 + bp]      = a00;
    redL[jh * 512 + (2 * g2)     * 64 + bp + 32] = a01;
    redL[jh * 512 + (2 * g2 + 1) * 64 + bp]      = a10;
    redL[jh * 512 + (2 * g2 + 1) * 64 + bp + 32] = a11;
    __syncthreads();

    if (tid < 128) {
        float pre[4];
#pragma unroll
        for (int g = 0; g < 4; g++) {
            int cl = 2 * g + uq;
            pre[g] = xw[g] + redL[cl * 64 + ub] + redL[512 + cl * 64 + ub];
        }
        float is = 1.f / (1.f + __expf(-pre[0]));
        float fs = 1.f / (1.f + __expf(-pre[1]));
        float gt = tanhf(pre[2]);
        float os = 1.f / (1.f + __expf(-pre[3]));
        float cnew = fs * cold + is * gt;
        float hnew = os * tanhf(cnew);
        cG[ub * HID + u0 + uq] = cnew;
        hG[(size_t)((t + 1) & 1) * 32768 + ub * HID + u0 + uq] = (_Float16)hnew;
        if (t == STEPS - 1) hfinal[ub * HID + u0 + uq] = hnew;
    }
}

// ---------------- K3: out = h @ Wout^T + bout ----------------
__global__ __launch_bounds__(128) void k_out(const float* __restrict__ Wout,
                                             const float* __restrict__ bout,
                                             const float* __restrict__ hfinal,
                                             float* __restrict__ out) {
    __shared__ float hl[BATCH * 128];
    const int tid = threadIdx.x;
    const int n = blockIdx.x * 128 + tid;
    const bool valid = n < NCLASS;
    float acc[BATCH];
#pragma unroll
    for (int b = 0; b < BATCH; b++) acc[b] = 0.f;
    const float4* W4 = (const float4*)Wout;
    const float4* h4 = (const float4*)hfinal;
    float4* hl4 = (float4*)hl;

    for (int kq = 0; kq < 4; kq++) {
        __syncthreads();
#pragma unroll
        for (int i = 0; i < 16; i++) {
            int f = i * 128 + tid;
            int b = f >> 5, kk = f & 31;
            hl4[f] = h4[b * 128 + kq * 32 + kk];
        }
        __syncthreads();
        if (valid) {
            for (int kk = 0; kk < 32; kk++) {
                float4 wv = W4[(size_t)n * 128 + kq * 32 + kk];
#pragma unroll
                for (int b = 0; b < BATCH; b++) {
                    float4 hv = hl4[b * 32 + kk];
                    acc[b] = fmaf(wv.x, hv.x, acc[b]);
                    acc[b] = fmaf(wv.y, hv.y, acc[b]);
                    acc[b] = fmaf(wv.z, hv.z, acc[b]);
                    acc[b] = fmaf(wv.w, hv.w, acc[b]);
                }
            }
        }
    }
    if (valid) {
        float bv = bout[n];
        for (int b = 0; b < BATCH; b++)
            out[(size_t)b * NCLASS + n] = acc[b] + bv;
    }
}

// ---------------- launch ----------------

extern "C" void kernel_launch(void* const* d_in, const int* in_sizes, int n_in,
                              void* d_out, int out_size, void* d_ws, size_t ws_size,
                              hipStream_t stream) {
    const int*   X    = (const int*)  d_in[0];
    const float* emb  = (const float*)d_in[1];
    const float* Wi   = (const float*)d_in[2];
    const float* Wh   = (const float*)d_in[3];
    const float* bi   = (const float*)d_in[4];
    const float* bh   = (const float*)d_in[5];
    const float* Wout = (const float*)d_in[10];
    const float* bout = (const float*)d_in[11];
    float* out = (float*)d_out;

    char* w = (char*)d_ws;
    float*          XWT    = (float*)(w);                           // 134217728 B
    unsigned short* XA     = (unsigned short*)(w + 134217728);      //  16777216 B (K1 only)
    // hG/cG aliased into XA tail — zeroed AFTER k_gemm1 consumed XA:
    _Float16*       hG     = (_Float16*)(w + 150732800);            //    131072 B (2 bufs)
    float*          cG     = (float*)(w + 150863872);               //    131072 B
    unsigned short* WiT    = (unsigned short*)(w + 150994944);      //   2097152 B
    _Float16*       WhT    = (_Float16*)(w + 153092096);            //   2097152 B
    float*          bias   = (float*)(w + 155189248);               //      8192 B
    float*          hfinal = (float*)(w + 155197440);               //    131072 B
    // total footprint unchanged: 155328512 B

    k_bias  <<<8,    256, 0, stream>>>(bi, bh, bias);
    k_wit   <<<2048,  64, 0, stream>>>(Wi, WiT);
    k_whT   <<<2048,  64, 0, stream>>>(Wh, WhT);
    k_gather<<<4096, 256, 0, stream>>>(X, emb, XA);
    k_gemm1 <<<dim3(32, 256), 256, 0, stream>>>(XA, WiT, bias, XWT);
    k_zero  <<<256,  256, 0, stream>>>((int*)hG, 65536);            // hG[2] + cG
    for (int t = 0; t < STEPS; t++)
        k_step<<<256, 256, 0, stream>>>(XWT, WhT, hG, cG, hfinal, t);
    k_out   <<<393,  128, 0, stream>>>(Wout, bout, hfinal, out);
}